// Round 1
// baseline (128.748 us; speedup 1.0000x reference)
//
#include <hip/hip_runtime.h>
#include <math.h>

#define NCELL 195   // number of ReLU cells
#define ICC   196   // input channels per point

// One ReLU cell: z=[xi,y] -> Linear(2,6) -> ReLU -> Linear(6,1) -> ReLU
// W1 layout [cell][2][6], b1 [cell][6], W2 [cell][6], b2 [cell]
__device__ __forceinline__ float cell_step(float xi, float y, int i,
    const float* __restrict__ W1, const float* __restrict__ b1,
    const float* __restrict__ W2, const float* __restrict__ b2)
{
    const float* w1 = W1 + i * 12;   // row0: x-weights, row1: y-weights
    const float* bb = b1 + i * 6;
    const float* w2 = W2 + i * 6;
    float h0 = fmaxf(fmaf(y, w1[6],  fmaf(xi, w1[0], bb[0])), 0.0f);
    float h1 = fmaxf(fmaf(y, w1[7],  fmaf(xi, w1[1], bb[1])), 0.0f);
    float h2 = fmaxf(fmaf(y, w1[8],  fmaf(xi, w1[2], bb[2])), 0.0f);
    float h3 = fmaxf(fmaf(y, w1[9],  fmaf(xi, w1[3], bb[3])), 0.0f);
    float h4 = fmaxf(fmaf(y, w1[10], fmaf(xi, w1[4], bb[4])), 0.0f);
    float h5 = fmaxf(fmaf(y, w1[11], fmaf(xi, w1[5], bb[5])), 0.0f);
    // 6-term dot as a short tree to cut the dependent chain
    float a0 = fmaf(h0, w2[0], fmaf(h1, w2[1], b2[i]));
    float a1 = fmaf(h2, w2[2], h3 * w2[3]);
    float a2 = fmaf(h4, w2[4], h5 * w2[5]);
    return fmaxf(a0 + (a1 + a2), 0.0f);
}

__global__ __launch_bounds__(256) void rnn_kernel(
    const float* __restrict__ x,    // [P, 196]
    const float* __restrict__ W1,   // [195, 2, 6]
    const float* __restrict__ b1,   // [195, 6]
    const float* __restrict__ W2,   // [195, 6]
    const float* __restrict__ b2,   // [195]
    const float* __restrict__ Wf1,  // [2, 6]
    const float* __restrict__ bf1,  // [6]
    const float* __restrict__ Wf2,  // [6]
    const float* __restrict__ bf2,  // [1]
    float* __restrict__ out,        // [P]
    int npoints)
{
    const int p = blockIdx.x * 256 + threadIdx.x;
    if (p >= npoints) return;

    // each point's row is 196 f32 = 49 float4, 16B-aligned (784 % 16 == 0)
    const float4* __restrict__ xr =
        reinterpret_cast<const float4*>(x) + (size_t)p * (ICC / 4);

    float4 cur = xr[0];
    float y = cur.x;             // y0 = x[...,0]

    // chunks 0..47 cover cells 0..191; prefetch next float4 each iter
    #pragma unroll 1
    for (int q = 0; q < 48; ++q) {
        float4 nxt = xr[q + 1];
        const int i0 = q * 4;
        y = cell_step(cur.x, y, i0 + 0, W1, b1, W2, b2);
        y = cell_step(cur.y, y, i0 + 1, W1, b1, W2, b2);
        y = cell_step(cur.z, y, i0 + 2, W1, b1, W2, b2);
        y = cell_step(cur.w, y, i0 + 3, W1, b1, W2, b2);
        cur = nxt;
    }
    // cur = xr[48] holds x[192..195]: cells 192..194, then the final sigmoid cell
    y = cell_step(cur.x, y, 192, W1, b1, W2, b2);
    y = cell_step(cur.y, y, 193, W1, b1, W2, b2);
    y = cell_step(cur.z, y, 194, W1, b1, W2, b2);

    const float xf = cur.w;      // x[...,195]
    float t = bf2[0];
    float hf0 = fmaxf(fmaf(y, Wf1[6],  fmaf(xf, Wf1[0], bf1[0])), 0.0f);
    float hf1 = fmaxf(fmaf(y, Wf1[7],  fmaf(xf, Wf1[1], bf1[1])), 0.0f);
    float hf2 = fmaxf(fmaf(y, Wf1[8],  fmaf(xf, Wf1[2], bf1[2])), 0.0f);
    float hf3 = fmaxf(fmaf(y, Wf1[9],  fmaf(xf, Wf1[3], bf1[3])), 0.0f);
    float hf4 = fmaxf(fmaf(y, Wf1[10], fmaf(xf, Wf1[4], bf1[4])), 0.0f);
    float hf5 = fmaxf(fmaf(y, Wf1[11], fmaf(xf, Wf1[5], bf1[5])), 0.0f);
    float a0 = fmaf(hf0, Wf2[0], fmaf(hf1, Wf2[1], t));
    float a1 = fmaf(hf2, Wf2[2], hf3 * Wf2[3]);
    float a2 = fmaf(hf4, Wf2[4], hf5 * Wf2[5]);
    t = a0 + (a1 + a2);

    out[p] = 1.0f / (1.0f + __expf(-t));   // sigmoid
}

extern "C" void kernel_launch(void* const* d_in, const int* in_sizes, int n_in,
                              void* d_out, int out_size, void* d_ws, size_t ws_size,
                              hipStream_t stream) {
    const float* x   = (const float*)d_in[0];
    const float* W1  = (const float*)d_in[1];
    const float* b1  = (const float*)d_in[2];
    const float* W2  = (const float*)d_in[3];
    const float* b2  = (const float*)d_in[4];
    const float* Wf1 = (const float*)d_in[5];
    const float* bf1 = (const float*)d_in[6];
    const float* Wf2 = (const float*)d_in[7];
    const float* bf2 = (const float*)d_in[8];
    float* out = (float*)d_out;

    const int npoints = out_size;                 // B*N = 262144
    const int block = 256;
    const int grid = (npoints + block - 1) / block;
    rnn_kernel<<<grid, block, 0, stream>>>(x, W1, b1, W2, b2,
                                           Wf1, bf1, Wf2, bf2, out, npoints);
}